// Round 6
// baseline (169.522 us; speedup 1.0000x reference)
//
#include <hip/hip_runtime.h>

// Problem constants (setup_inputs: B=256, T=16, H=W=160, sms=2 -> t=16, h=w=80)
#define T_DIM 16
#define H2 80
#define W2 80
#define SLICE (H2 * W2)          // 6400 floats per t-slice
#define SAMPLE (T_DIM * SLICE)   // 102400 floats per sample
#define BANDS 5                  // 16-row bands per slice
#define ROWS_PER_BAND (H2 / BANDS)   // 16
#define F4_PER_BAND (ROWS_PER_BAND * W2 / 4)  // 320 float4 slots per band-slice
#define TSPLIT 2                 // t-halves per sample
#define TCHUNK (T_DIM / TSPLIT)  // 8 slices per block
#define BLOCK 256                // 4 waves -- clean residency granularity
#define PARTS (BANDS * TSPLIT)   // 10 partials per sample

__device__ __forceinline__ float4 relu4(float4 v) {
    v.x = fmaxf(v.x, 0.f); v.y = fmaxf(v.y, 0.f);
    v.z = fmaxf(v.z, 0.f); v.w = fmaxf(v.w, 0.f);
    return v;
}

// One slot-step: own float4 + h-neighbor float4 + w-boundary scalar, all
// from global (L1-hit for neighbors). Accumulates the 7 partial sums.
// This is exactly the round-0 data path (fastest measured) -- no shuffles.
__device__ __forceinline__ void slot_step(const float* __restrict__ sl,
                                          int rowOff, int hOff, int wOff,
                                          float yy,
                                          float xx0, float xx1, float xx2, float xx3,
                                          float cq0, float cq1, float cq2, float cq3,
                                          float4& prev, bool firstT,
                                          float& s0, float& sx, float& sy, float& sq,
                                          float& tvh, float& tvw, float& tvt) {
    const float4 v  = relu4(*(const float4*)(sl + rowOff));
    const float4 hN = relu4(*(const float4*)(sl + hOff));
    const float  wN = fmaxf(sl[wOff], 0.f);

    const float rs = (v.x + v.y) + (v.z + v.w);
    s0 += rs;
    sy = fmaf(yy, rs, sy);
    sx = fmaf(xx0, v.x, sx); sx = fmaf(xx1, v.y, sx);
    sx = fmaf(xx2, v.z, sx); sx = fmaf(xx3, v.w, sx);
    sq = fmaf(cq0, v.x, sq); sq = fmaf(cq1, v.y, sq);
    sq = fmaf(cq2, v.z, sq); sq = fmaf(cq3, v.w, sq);

    tvw += fabsf(v.y - v.x) + fabsf(v.z - v.y) + fabsf(v.w - v.z)
         + fabsf(wN - v.w);
    tvh += fabsf(hN.x - v.x) + fabsf(hN.y - v.y) +
           fabsf(hN.z - v.z) + fabsf(hN.w - v.w);
    if (!firstT) {
        tvt += fabsf(v.x - prev.x) + fabsf(v.y - prev.y) +
               fabsf(v.z - prev.z) + fabsf(v.w - prev.w);
    }
    prev = v;
}

// Phase 1, occupancy-repack of the round-0 structure:
//   - 256-thread (4-wave) blocks instead of 320-thread (5-wave). The band's
//     320 f4 slots: every thread owns slot tid; wave 0 (tid<64, wave-uniform
//     branch) additionally owns slot tid+256.
//   - t split in halves (grid x2 = 2560 blocks = 10 blocks/CU of work);
//     half 1 seeds prev from slice 7 so the (7,8) t-pair is counted once.
//   - __launch_bounds__(256, 6): cap VGPR for >=6 waves/SIMD residency.
// Data path unchanged from round 0 (fastest measured): coalesced own float4,
// h-row reload (L1 hit), w-boundary scalar, register-resident t-diff,
// NO cross-lane ops, NO barriers in the hot loop.
__global__ __launch_bounds__(BLOCK, 6) void tsr_phase1(const float* __restrict__ scores,
                                                       float* __restrict__ ws) {
    __shared__ float red[(BLOCK / 64) * 7];

    const int blk  = blockIdx.x;
    const int b    = blk / PARTS;
    const int part = blk % PARTS;
    const int band = part >> 1;      // 0..4
    const int half = part & 1;       // 0..1
    const int tid  = threadIdx.x;
    const int lane = tid & 63;
    const bool two = (tid < 64);     // wave 0 handles a second slot

    const float step = 2.0f / (float)(H2 - 1);

    // ---- slot geometry (slot j in [0,320) within the band) ----
    // j -> row-in-band rb=j/20, f4-col cxq=j%20
    const int j0 = tid;
    const int j1 = tid + 256;        // valid only when two

    const int rb0 = j0 / 20, cx0 = j0 % 20;
    const int rb1 = j1 / 20, cx1 = j1 % 20;
    const int y0 = band * ROWS_PER_BAND + rb0;
    const int y1 = band * ROWS_PER_BAND + rb1;   // <80 only when two
    const int xb0 = cx0 * 4, xb1 = cx1 * 4;

    const int rowOff0 = y0 * W2 + xb0;
    const int rowOff1 = y1 * W2 + xb1;
    const int hOff0 = (y0 + 1 < H2) ? rowOff0 + W2 : rowOff0;  // clamp -> diff 0
    const int hOff1 = (y1 + 1 < H2) ? rowOff1 + W2 : rowOff1;
    const int wOff0 = (cx0 < 19) ? rowOff0 + 4 : rowOff0 + 3;  // clamp -> diff 0
    const int wOff1 = (cx1 < 19) ? rowOff1 + 4 : rowOff1 + 3;

    const float yyA = -1.0f + (float)y0 * step;
    const float yyB = -1.0f + (float)y1 * step;
    const float a0 = -1.0f + (float)xb0 * step, a1 = a0 + step, a2 = a1 + step, a3 = a2 + step;
    const float b0 = -1.0f + (float)xb1 * step, b1 = b0 + step, b2 = b1 + step, b3 = b2 + step;
    const float yyA2 = yyA * yyA, yyB2 = yyB * yyB;
    const float ca0 = a0 * a0 + yyA2, ca1 = a1 * a1 + yyA2;
    const float ca2 = a2 * a2 + yyA2, ca3 = a3 * a3 + yyA2;
    const float cb0 = b0 * b0 + yyB2, cb1 = b1 * b1 + yyB2;
    const float cb2 = b2 * b2 + yyB2, cb3 = b3 * b3 + yyB2;

    const float* tb = scores + (size_t)b * SAMPLE + (size_t)(half * TCHUNK) * SLICE;

    float s0 = 0.f, sx = 0.f, sy = 0.f, sq = 0.f;
    float tvh = 0.f, tvw = 0.f, tvt = 0.f;

    // seed prev for the t-diff: half 1 from slice TCHUNK-1 of half 0
    // (pair (7,8) counted here); half 0 first iteration contributes 0.
    float4 prev0 = make_float4(0.f, 0.f, 0.f, 0.f);
    float4 prev1 = prev0;
    bool firstT = (half == 0);
    if (half > 0) {
        const float* sl = tb - SLICE;
        prev0 = relu4(*(const float4*)(sl + rowOff0));
        if (two) prev1 = relu4(*(const float4*)(sl + rowOff1));
    }

#pragma unroll 4
    for (int i = 0; i < TCHUNK; ++i) {
        const float* sl = tb + (size_t)i * SLICE;
        slot_step(sl, rowOff0, hOff0, wOff0, yyA, a0, a1, a2, a3,
                  ca0, ca1, ca2, ca3, prev0, firstT,
                  s0, sx, sy, sq, tvh, tvw, tvt);
        if (two) {  // wave-uniform branch: all of wave 0, none of waves 1-3
            slot_step(sl, rowOff1, hOff1, wOff1, yyB, b0, b1, b2, b3,
                      cb0, cb1, cb2, cb3, prev1, firstT,
                      s0, sx, sy, sq, tvh, tvw, tvt);
        }
        firstT = false;
    }

    // block reduction: wave shuffle, then cross-wave via LDS
    float acc[7] = {s0, sx, sy, sq, tvh, tvw, tvt};
#pragma unroll
    for (int off = 32; off > 0; off >>= 1) {
#pragma unroll
        for (int i = 0; i < 7; ++i) acc[i] += __shfl_down(acc[i], off);
    }
    const int wave = tid >> 6;
    if (lane == 0) {
#pragma unroll
        for (int i = 0; i < 7; ++i) red[wave * 7 + i] = acc[i];
    }
    __syncthreads();
    if (tid < 7) {
        float s = 0.f;
#pragma unroll
        for (int wv = 0; wv < BLOCK / 64; ++wv) s += red[wv * 7 + tid];
        ws[blk * 8 + tid] = s;  // distinct slot per block -> no init, no atomics
    }
}

// Phase 2: sum the 10 partials per sample, nonlinear combine, batch mean
__global__ __launch_bounds__(256) void tsr_finalize(const float* __restrict__ ws,
                                                    float* __restrict__ out, int B) {
    __shared__ float red[256];
    const int tid = threadIdx.x;
    float acc = 0.f;
    const float ch = 1.0f / (float)(T_DIM * (H2 - 1) * W2);       // 1/101120
    const float cw = 1.0f / (float)(T_DIM * H2 * (W2 - 1));       // 1/101120
    const float ct = 0.3f / (float)((T_DIM - 1) * H2 * W2);       // 0.3/96000
    for (int b = tid; b < B; b += 256) {
        float p[7] = {0.f, 0.f, 0.f, 0.f, 0.f, 0.f, 0.f};
        for (int part = 0; part < PARTS; ++part) {
            const float* w = ws + (size_t)(b * PARTS + part) * 8;
#pragma unroll
            for (int i = 0; i < 7; ++i) p[i] += w[i];
        }
        const float S0 = p[0], Sx = p[1], Sy = p[2], Sq = p[3];
        const float Th = p[4], Tw = p[5], Tt = p[6];
        const float tot = fmaxf(S0, 1e-6f);
        const float inv = 1.0f / tot;
        const float mux = Sx * inv, muy = Sy * inv;
        const float m2 = mux * mux + muy * muy;
        const float compact = Sq * inv - 2.0f * m2 + m2 * (S0 * inv);
        const float tv = Th * ch + Tw * cw + Tt * ct;
        acc += compact + tv;
    }
    red[tid] = acc;
    __syncthreads();
    for (int s = 128; s > 0; s >>= 1) {
        if (tid < s) red[tid] += red[tid + s];
        __syncthreads();
    }
    if (tid == 0) out[0] = red[0] / (float)B;
}

extern "C" void kernel_launch(void* const* d_in, const int* in_sizes, int n_in,
                              void* d_out, int out_size, void* d_ws, size_t ws_size,
                              hipStream_t stream) {
    const float* scores = (const float*)d_in[0];
    const int B = in_sizes[0] / SAMPLE;  // 256
    float* ws = (float*)d_ws;

    tsr_phase1<<<B * PARTS, BLOCK, 0, stream>>>(scores, ws);
    tsr_finalize<<<1, 256, 0, stream>>>(ws, (float*)d_out, B);
}